// Round 12
// baseline (277.434 us; speedup 1.0000x reference)
//
#include <hip/hip_runtime.h>
#include <math.h>

static inline int cdiv(long a, long b){ return (int)((a + b - 1) / b); }
static inline char* alignp(char* p, size_t a){ return (char*)(((uintptr_t)p + a - 1) & ~(uintptr_t)(a - 1)); }

typedef __attribute__((ext_vector_type(8))) short bf16x8;
typedef __attribute__((ext_vector_type(4))) short bf16x4;
typedef __attribute__((ext_vector_type(4))) float f32x4;

__device__ __forceinline__ float lrelu(float x){ return x > 0.f ? x : 0.2f * x; }
__device__ __forceinline__ float eluf(float x){ return x > 0.f ? x : __expf(x) - 1.f; }
__device__ __forceinline__ short f2bf(float f){            // RNE f32 -> bf16 bits
  unsigned u = __float_as_uint(f);
  return (short)((u + 0x7FFFu + ((u >> 16) & 1u)) >> 16);
}
__device__ __forceinline__ float bflo(unsigned v){ return __uint_as_float(v << 16); }
__device__ __forceinline__ float bfhi(unsigned v){ return __uint_as_float(v & 0xFFFF0000u); }

// ======================= MFMA GEMM: 32 rows per wave (2 A-frags share each B-load) =======================
template<int K, int FOUT, bool DOTS>
__global__ void k_gemm_mfma(const short* __restrict__ Abf, const short* __restrict__ Wp,
                            short* __restrict__ outb,
                            const float* __restrict__ av_s, const float* __restrict__ av_d,
                            float* __restrict__ as_, float* __restrict__ ad_, int N){
  constexpr int NKS = K / 32, NCT = FOUT / 16;
  int wid  = threadIdx.x >> 6;
  int lane = threadIdx.x & 63;
  int rowbase = (blockIdx.x * 4 + wid) * 32;
  if(rowbase >= N) return;
  int arow0 = rowbase + (lane & 15);
  int arow1 = rowbase + 16 + (lane & 15);
  if(arow0 >= N) arow0 = N - 1;                   // clamp; clamped rows never stored
  if(arow1 >= N) arow1 = N - 1;
  f32x4 acc0[NCT] = {}, acc1[NCT] = {};
  const short* ap0 = Abf + (long)arow0 * K + (lane >> 4) * 8;
  const short* ap1 = Abf + (long)arow1 * K + (lane >> 4) * 8;
  #pragma unroll
  for(int ks = 0; ks < NKS; ++ks){
    bf16x8 a0 = *(const bf16x8*)(ap0 + ks * 32);
    bf16x8 a1 = *(const bf16x8*)(ap1 + ks * 32);
    #pragma unroll
    for(int ct = 0; ct < NCT; ++ct){
      bf16x8 b = *(const bf16x8*)(Wp + ((ks * NCT + ct) * 64 + lane) * 8);
      acc0[ct] = __builtin_amdgcn_mfma_f32_16x16x32_bf16(a0, b, acc0[ct], 0, 0, 0);
      acc1[ct] = __builtin_amdgcn_mfma_f32_16x16x32_bf16(a1, b, acc1[ct], 0, 0, 0);
    }
  }
  int rq = (lane >> 4) * 4;                        // D: row=(lane>>4)*4+j, col=lane&15
  int c0 = lane & 15;
  #pragma unroll
  for(int j = 0; j < 4; ++j){
    int r = rowbase + rq + j;
    if(r < N){
      #pragma unroll
      for(int ct = 0; ct < NCT; ++ct)
        outb[(long)r * FOUT + ct * 16 + c0] = f2bf(acc0[ct][j]);
    }
    int r1 = rowbase + 16 + rq + j;
    if(r1 < N){
      #pragma unroll
      for(int ct = 0; ct < NCT; ++ct)
        outb[(long)r1 * FOUT + ct * 16 + c0] = f2bf(acc1[ct][j]);
    }
  }
  if(DOTS){
    float avs[NCT], avd[NCT];
    #pragma unroll
    for(int ct = 0; ct < NCT; ++ct){ avs[ct] = av_s[ct * 16 + c0]; avd[ct] = av_d[ct * 16 + c0]; }
    #pragma unroll
    for(int j = 0; j < 4; ++j){
      float ps = 0.f, pd = 0.f;
      #pragma unroll
      for(int ct = 0; ct < NCT; ++ct){
        float hv = acc0[ct][j];
        ps = fmaf(hv, avs[ct], ps);
        pd = fmaf(hv, avd[ct], pd);
      }
      #pragma unroll
      for(int off = 1; off < 16; off <<= 1){
        ps += __shfl_xor(ps, off);
        pd += __shfl_xor(pd, off);
      }
      int r = rowbase + rq + j;
      if(c0 == 0 && r < N){ as_[r] = ps; ad_[r] = pd; }
    }
    #pragma unroll
    for(int j = 0; j < 4; ++j){
      float ps = 0.f, pd = 0.f;
      #pragma unroll
      for(int ct = 0; ct < NCT; ++ct){
        float hv = acc1[ct][j];
        ps = fmaf(hv, avs[ct], ps);
        pd = fmaf(hv, avd[ct], pd);
      }
      #pragma unroll
      for(int off = 1; off < 16; off <<= 1){
        ps += __shfl_xor(ps, off);
        pd += __shfl_xor(pd, off);
      }
      int r = rowbase + 16 + rq + j;
      if(c0 == 0 && r < N){ as_[r] = ps; ad_[r] = pd; }
    }
  }
}

// ======================= merged prep: weight packs (blocks 0-20) + layer1 (blocks 21+) =======================
template<int K, int FOUT>
__device__ __forceinline__ void pack_dev(const float* __restrict__ W, short* __restrict__ Wp, int idx){
  constexpr int NKS = K / 32, NCT = FOUT / 16;
  if(idx >= NKS * NCT * 64) return;
  int lane = idx & 63;
  int ct = (idx >> 6) % NCT;
  int ks = (idx >> 6) / NCT;
  int col = ct * 16 + (lane & 15);
  int kb  = ks * 32 + (lane >> 4) * 8;
  #pragma unroll
  for(int j = 0; j < 8; ++j) Wp[idx * 8 + j] = f2bf(W[(kb + j) * FOUT + col]);
}
__global__ void k_prep(const float* __restrict__ W2, const float* __restrict__ W3,
                       const float* __restrict__ Wg1, const float* __restrict__ Wg2,
                       const float* __restrict__ W1, const float* __restrict__ a1s,
                       const float* __restrict__ a1d, const float* __restrict__ x,
                       short* __restrict__ Wp2, short* __restrict__ Wp3,
                       short* __restrict__ Wpg1, short* __restrict__ Wpg2,
                       short* __restrict__ outb, float* __restrict__ as_,
                       float* __restrict__ ad_, int N){
  int b = blockIdx.x;
  if(b < 8){       pack_dev<128,128>(W2,  Wp2,  b * 256 + threadIdx.x); return; }
  if(b < 16){      pack_dev<128,128>(W3,  Wp3,  (b - 8) * 256 + threadIdx.x); return; }
  if(b < 20){      pack_dev<128, 64>(Wg1, Wpg1, (b - 16) * 256 + threadIdx.x); return; }
  if(b == 20){     pack_dev< 64, 32>(Wg2, Wpg2, threadIdx.x); return; }
  // layer-1 blocks: self-compute S = (W1.a1s, W1.a1d), then outer product + dots
  __shared__ float s1[128], s2[128];
  int t = threadIdx.x;
  if(t < 128){ float w = W1[t]; s1[t] = w * a1s[t]; s2[t] = w * a1d[t]; }
  __syncthreads();
  for(int off = 64; off > 0; off >>= 1){
    if(t < off){ s1[t] += s1[t + off]; s2[t] += s2[t + off]; }
    __syncthreads();
  }
  float S0 = s1[0], S1 = s2[0];
  long idx = (long)(b - 21) * blockDim.x + t;
  if(idx >= (long)N * 16) return;
  int node = (int)(idx >> 4), j8 = ((int)idx & 15) * 8;
  float xv = x[node];
  float4 w0 = *(const float4*)(W1 + j8);
  float4 w1 = *(const float4*)(W1 + j8 + 4);
  bf16x8 v;
  v[0] = f2bf(xv * w0.x); v[1] = f2bf(xv * w0.y);
  v[2] = f2bf(xv * w0.z); v[3] = f2bf(xv * w0.w);
  v[4] = f2bf(xv * w1.x); v[5] = f2bf(xv * w1.y);
  v[6] = f2bf(xv * w1.z); v[7] = f2bf(xv * w1.w);
  *(bf16x8*)(outb + (long)node * 128 + j8) = v;
  if((idx & 15) == 0){ as_[node] = xv * S0; ad_[node] = xv * S1; }
}

// ======================= CSR build (dst-sorted, with self-loops) =======================
// deg[] is memset(0); the self-loop "+1" is folded into the scans below.
// XCD-partitioned: block p=blockIdx&7 handles dst range [p*Pdiv,(p+1)*Pdiv) only
__global__ void k_deg_count8(const int* __restrict__ ei, int E, int Pdiv,
                             int* __restrict__ deg){
  int p = blockIdx.x & 7;
  int lo = p * Pdiv, hi = lo + Pdiv;
  long stride = (long)(gridDim.x >> 3) * blockDim.x;
  for(long e = (long)(blockIdx.x >> 3) * blockDim.x + threadIdx.x; e < E; e += stride){
    int d = ei[E + e];
    if(d >= lo && d < hi) atomicAdd(&deg[d], 1);
  }
}

// ---- hierarchical exclusive scan of (deg[N]+1) -> rowptr[N+1], cursor[N], dinv[N] ----
__global__ void k_scan_part(const int* __restrict__ deg, int* __restrict__ bsum, int N){
  __shared__ int red[256];
  int i = blockIdx.x * 256 + threadIdx.x;
  int v = (i < N) ? deg[i] + 1 : 0;
  red[threadIdx.x] = v;
  __syncthreads();
  #pragma unroll
  for(int off = 128; off > 0; off >>= 1){
    if(threadIdx.x < off) red[threadIdx.x] += red[threadIdx.x + off];
    __syncthreads();
  }
  if(threadIdx.x == 0) bsum[blockIdx.x] = red[0];
}
__global__ void k_scan_mid(int* __restrict__ bsum, int NB, int* __restrict__ rowptr, int N){
  __shared__ int buf[1024];
  int t = threadIdx.x;
  int v = (t < NB) ? bsum[t] : 0;
  buf[t] = v;
  __syncthreads();
  for(int off = 1; off < 1024; off <<= 1){
    int u = (t >= off) ? buf[t - off] : 0;
    __syncthreads();
    buf[t] += u;
    __syncthreads();
  }
  if(t < NB) bsum[t] = buf[t] - v;                // exclusive
  if(t == 1023) rowptr[N] = buf[1023];
}
__global__ void k_scan_fin(const int* __restrict__ deg, const int* __restrict__ bsum,
                           int* __restrict__ rowptr, int* __restrict__ cursor,
                           float* __restrict__ dinv, int N){
  __shared__ int buf[256];
  int i = blockIdx.x * 256 + threadIdx.x;
  int t = threadIdx.x;
  int v = (i < N) ? deg[i] + 1 : 0;
  buf[t] = v;
  __syncthreads();
  #pragma unroll
  for(int off = 1; off < 256; off <<= 1){
    int u = (t >= off) ? buf[t - off] : 0;
    __syncthreads();
    buf[t] += u;
    __syncthreads();
  }
  if(i < N){
    int ex = buf[t] - v + bsum[blockIdx.x];
    rowptr[i] = ex; cursor[i] = ex;
    dinv[i] = rsqrtf((float)v);                   // v >= 1 (self-loop)
  }
}

// XCD-partitioned CSR fill
__global__ void k_fill8(const int* __restrict__ ei, int E, int N, int Pdiv,
                        int* __restrict__ cursor, int* __restrict__ csr){
  int p = blockIdx.x & 7;
  int lo = p * Pdiv, hi = lo + Pdiv;
  long ET = (long)E + N;
  long stride = (long)(gridDim.x >> 3) * blockDim.x;
  for(long e = (long)(blockIdx.x >> 3) * blockDim.x + threadIdx.x; e < ET; e += stride){
    int d = (e < E) ? ei[E + e] : (int)(e - E);
    if(d < lo || d >= hi) continue;
    int s = (e < E) ? ei[e] : d;
    int pos = atomicAdd(&cursor[d], 1);
    csr[pos] = s;
  }
}

// ======================= fused GAT aggregation: TWO dst per wave, 8-deep load batching =======================
__global__ void k_gat_agg(const int* __restrict__ rowptr, const int* __restrict__ csr,
                          const float* __restrict__ as_, const float* __restrict__ ad_,
                          const short* __restrict__ h, const float* __restrict__ bias,
                          short* __restrict__ out, int N){
  int pair = (int)(((long)blockIdx.x * blockDim.x + threadIdx.x) >> 6);
  if(pair * 2 >= N) return;
  int lane = threadIdx.x & 63;
  int half = lane >> 5, hl = lane & 31;
  int w = pair * 2 + half;
  bool active = (w < N);
  int start = 0, end = 0, deg = 0;
  float add = 0.f;
  if(active){ start = rowptr[w]; end = rowptr[w + 1]; deg = end - start; add = ad_[w]; }

  int s_reg = 0;
  float logit = -INFINITY;
  if(hl < deg){                                  // implies active
    s_reg = csr[start + hl];
    logit = lrelu(as_[s_reg] + add);
  }
  float m, inv, alpha_reg;
  if(deg <= 32){
    // fast path: per-half 3-phase softmax (offsets <=16 never cross the half)
    m = logit;
    #pragma unroll
    for(int off = 16; off > 0; off >>= 1) m = fmaxf(m, __shfl_xor(m, off));
    float e = __expf(logit - m);                 // inactive lanes: exp(-INF)=0
    float ssum = e;
    #pragma unroll
    for(int off = 16; off > 0; off >>= 1) ssum += __shfl_xor(ssum, off);
    inv = 1.f / (ssum + 1e-16f);
    alpha_reg = e * inv;
  }else{
    // rare overflow: per-lane online over strided edges, then per-half merge
    float mm = logit, ssum = (hl < deg) ? 1.f : 0.f;
    for(int e = start + hl + 32; e < end; e += 32){
      int s = csr[e];
      float l = lrelu(as_[s] + add);
      if(l > mm){ ssum = ssum * __expf(mm - l) + 1.f; mm = l; }
      else        ssum += __expf(l - mm);
    }
    #pragma unroll
    for(int off = 16; off > 0; off >>= 1){
      float mo = __shfl_xor(mm, off);
      float so = __shfl_xor(ssum, off);
      float mn = fmaxf(mm, mo);
      float ea = (mm > -INFINITY) ? __expf(mm - mn) : 0.f;
      float eb = (mo > -INFINITY) ? __expf(mo - mn) : 0.f;
      ssum = ssum * ea + so * eb;
      mm = mn;
    }
    m = mm;
    inv = 1.f / (ssum + 1e-16f);
    alpha_reg = __expf(logit - m) * inv;
  }

  // phase B: per half, 16 edges per outer iter (8 per 16-lane subgroup), all 8 loads
  // issued before any FMA -> 8 gathers in flight. Invalid slots clamp to edge 0 with a=0.
  float acc[8] = {};
  int nb = deg < 32 ? deg : 32;
  int gg = hl >> 4;
  int fo = (hl & 15) * 8;
  int base = half << 5;
  const short* hf = h + fo;
  for(int k = 0; k < nb; k += 16){
    uint4 hv[8]; float av[8];
    #pragma unroll
    for(int u = 0; u < 8; ++u){
      int idx = k + 2 * u + gg;
      bool ok = idx < nb;
      int sl = base + (ok ? idx : 0);
      float a = __shfl(alpha_reg, sl);
      av[u] = ok ? a : 0.f;
      int s  = __shfl(s_reg, sl);
      hv[u] = *(const uint4*)(hf + (long)s * 128);
    }
    #pragma unroll
    for(int u = 0; u < 8; ++u){
      acc[0] = fmaf(av[u], bflo(hv[u].x), acc[0]);
      acc[1] = fmaf(av[u], bfhi(hv[u].x), acc[1]);
      acc[2] = fmaf(av[u], bflo(hv[u].y), acc[2]);
      acc[3] = fmaf(av[u], bfhi(hv[u].y), acc[3]);
      acc[4] = fmaf(av[u], bflo(hv[u].z), acc[4]);
      acc[5] = fmaf(av[u], bfhi(hv[u].z), acc[5]);
      acc[6] = fmaf(av[u], bflo(hv[u].w), acc[6]);
      acc[7] = fmaf(av[u], bfhi(hv[u].w), acc[7]);
    }
  }
  for(int e = start + 32; e < end; ++e){          // rare overflow (subgroup 0 of half)
    if(hl < 16){
      int s = csr[e];
      float l = lrelu(as_[s] + add);
      float a = __expf(l - m) * inv;
      uint4 hv = *(const uint4*)(hf + (long)s * 128);
      acc[0] = fmaf(a, bflo(hv.x), acc[0]);
      acc[1] = fmaf(a, bfhi(hv.x), acc[1]);
      acc[2] = fmaf(a, bflo(hv.y), acc[2]);
      acc[3] = fmaf(a, bfhi(hv.y), acc[3]);
      acc[4] = fmaf(a, bflo(hv.z), acc[4]);
      acc[5] = fmaf(a, bfhi(hv.z), acc[5]);
      acc[6] = fmaf(a, bflo(hv.w), acc[6]);
      acc[7] = fmaf(a, bfhi(hv.w), acc[7]);
    }
  }
  #pragma unroll
  for(int j = 0; j < 8; ++j) acc[j] += __shfl_xor(acc[j], 16);
  if(active && hl < 16){
    float4 b0 = *(const float4*)(bias + fo);
    float4 b1 = *(const float4*)(bias + fo + 4);
    bf16x8 v;
    v[0] = f2bf(eluf(acc[0] + b0.x)); v[1] = f2bf(eluf(acc[1] + b0.y));
    v[2] = f2bf(eluf(acc[2] + b0.z)); v[3] = f2bf(eluf(acc[3] + b0.w));
    v[4] = f2bf(eluf(acc[4] + b1.x)); v[5] = f2bf(eluf(acc[5] + b1.y));
    v[6] = f2bf(eluf(acc[6] + b1.z)); v[7] = f2bf(eluf(acc[7] + b1.w));
    *(bf16x8*)(out + (long)w * 128 + fo) = v;
  }
}

// ======================= fused GCN aggregation: TWO dst per wave, 8-deep load batching =======================
template<int F, bool BFOUT>
__global__ void k_gcn_agg(const int* __restrict__ rowptr, const int* __restrict__ csr,
                          const float* __restrict__ dinv, const short* __restrict__ h,
                          const float* __restrict__ bias, short* __restrict__ out_bf,
                          float* __restrict__ out_f, int N){
  constexpr int FPL = F / 16;                     // features per lane (4 or 2)
  int pair = (int)(((long)blockIdx.x * blockDim.x + threadIdx.x) >> 6);
  if(pair * 2 >= N) return;
  int lane = threadIdx.x & 63;
  int half = lane >> 5, hl = lane & 31;
  int w = pair * 2 + half;
  bool active = (w < N);
  int start = 0, end = 0, deg = 0;
  float dd = 0.f;
  if(active){ start = rowptr[w]; end = rowptr[w + 1]; deg = end - start; dd = dinv[w]; }
  int s_reg = 0; float dv_reg = 0.f;
  if(hl < deg){
    s_reg = csr[start + hl];
    dv_reg = dinv[s_reg];
  }
  float acc[FPL] = {};
  int nb = deg < 32 ? deg : 32;
  int gg = hl >> 4;
  int fo = (hl & 15) * FPL;
  int base = half << 5;
  const short* hf = h + fo;
  for(int k = 0; k < nb; k += 16){
    uint2 hv4[8]; unsigned hv2[8]; float nv[8];
    #pragma unroll
    for(int u = 0; u < 8; ++u){
      int idx = k + 2 * u + gg;
      bool ok = idx < nb;
      int sl = base + (ok ? idx : 0);
      float nrm = dd * __shfl(dv_reg, sl);
      nv[u] = ok ? nrm : 0.f;
      int s = __shfl(s_reg, sl);
      if(FPL == 4) hv4[u] = *(const uint2*)(hf + (long)s * F);
      else         hv2[u] = *(const unsigned*)(hf + (long)s * F);
    }
    #pragma unroll
    for(int u = 0; u < 8; ++u){
      if(FPL == 4){
        acc[0] = fmaf(nv[u], bflo(hv4[u].x), acc[0]);
        acc[1] = fmaf(nv[u], bfhi(hv4[u].x), acc[1]);
        acc[2] = fmaf(nv[u], bflo(hv4[u].y), acc[2]);
        acc[3] = fmaf(nv[u], bfhi(hv4[u].y), acc[3]);
      }else{
        acc[0] = fmaf(nv[u], bflo(hv2[u]), acc[0]);
        acc[1] = fmaf(nv[u], bfhi(hv2[u]), acc[1]);
      }
    }
  }
  for(int e = start + 32; e < end; ++e){          // rare overflow (subgroup 0 of half)
    if(hl < 16){
      int s = csr[e];
      float nrm = dd * dinv[s];
      if(FPL == 4){
        uint2 hv = *(const uint2*)(hf + (long)s * F);
        acc[0] = fmaf(nrm, bflo(hv.x), acc[0]);
        acc[1] = fmaf(nrm, bfhi(hv.x), acc[1]);
        acc[2] = fmaf(nrm, bflo(hv.y), acc[2]);
        acc[3] = fmaf(nrm, bfhi(hv.y), acc[3]);
      }else{
        unsigned hv = *(const unsigned*)(hf + (long)s * F);
        acc[0] = fmaf(nrm, bflo(hv), acc[0]);
        acc[1] = fmaf(nrm, bfhi(hv), acc[1]);
      }
    }
  }
  #pragma unroll
  for(int j = 0; j < FPL; ++j) acc[j] += __shfl_xor(acc[j], 16);
  if(active && hl < 16){
    if(BFOUT){
      if(FPL == 4){
        bf16x4 v;
        #pragma unroll
        for(int j = 0; j < 4; ++j) v[j] = f2bf(eluf(acc[j] + bias[fo + j]));
        *(bf16x4*)(out_bf + (long)w * F + fo) = v;
      }else{
        #pragma unroll
        for(int j = 0; j < FPL; ++j)
          out_bf[(long)w * F + fo + j] = f2bf(eluf(acc[j] + bias[fo + j]));
      }
    }else{
      if(FPL == 2){
        float2 v2 = make_float2(eluf(acc[0] + bias[fo]), eluf(acc[1] + bias[fo + 1]));
        *(float2*)(out_f + (long)w * F + fo) = v2;
      }else{
        #pragma unroll
        for(int j = 0; j < FPL; ++j)
          out_f[(long)w * F + fo + j] = eluf(acc[j] + bias[fo + j]);
      }
    }
  }
}

// ============ per-graph softmax aggregation: chunked online (m,s,v) + combine ============
template<int S>
__global__ void k_bagg_part(const float* __restrict__ h, const int* __restrict__ batch,
                            const float* __restrict__ t, float* __restrict__ pM,
                            float* __restrict__ pS, float* __restrict__ pV, int N){
  int chunk = blockIdx.x;
  int b = chunk / S, s = chunk % S;
  __shared__ int s_lo, s_hi;
  if(threadIdx.x == 0){
    int lo = 0, hi = N;
    while(lo < hi){ int mid = (lo + hi) >> 1; if(batch[mid] < b) lo = mid + 1; else hi = mid; }
    s_lo = lo;
    int lo2 = lo, hi2 = N;
    while(lo2 < hi2){ int mid = (lo2 + hi2) >> 1; if(batch[mid] < b + 1) lo2 = mid + 1; else hi2 = mid; }
    s_hi = lo2;
  }
  __syncthreads();
  int lo = s_lo, hi = s_hi;
  int len = hi - lo;
  int per = (len + S - 1) / S;
  int clo = lo + s * per;
  int chi = clo + per; if(chi > hi) chi = hi;
  float tv = t[0];
  int c = threadIdx.x & 31, r = threadIdx.x >> 5;   // 8 rows x 32 channels

  float m = -INFINITY, ss = 0.f, vv = 0.f;
  for(int i = clo + r; i < chi; i += 8){
    float hv = h[(long)i * 32 + c];
    float l = hv * tv;
    if(l > m){
      float e = (m > -INFINITY) ? __expf(m - l) : 0.f;
      ss = ss * e + 1.f; vv = vv * e + hv; m = l;
    }else{
      float e = __expf(l - m);
      ss += e; vv += e * hv;
    }
  }
  __shared__ float rm[8][32], rs[8][32], rv[8][32];
  rm[r][c] = m; rs[r][c] = ss; rv[r][c] = vv;
  __syncthreads();
  if(r == 0){
    float M = rm[0][c], SS = rs[0][c], VV = rv[0][c];
    #pragma unroll
    for(int k = 1; k < 8; ++k){
      float mo = rm[k][c], so = rs[k][c], vo = rv[k][c];
      float mn = fmaxf(M, mo);
      float ea = (M  > -INFINITY) ? __expf(M  - mn) : 0.f;
      float eb = (mo > -INFINITY) ? __expf(mo - mn) : 0.f;
      SS = SS * ea + so * eb; VV = VV * ea + vo * eb; M = mn;
    }
    pM[chunk * 32 + c] = M; pS[chunk * 32 + c] = SS; pV[chunk * 32 + c] = VV;
  }
}

// ---- merged combine + heads: one block, 1024 threads ----
template<int S>
__global__ void k_final(const float* __restrict__ pM, const float* __restrict__ pS,
                        const float* __restrict__ pV, const float* __restrict__ Wl1,
                        const float* __restrict__ bl1, const float* __restrict__ Wl2,
                        const float* __restrict__ bl2, float* __restrict__ out, int B){
  __shared__ float gs[4096];
  int t = threadIdx.x;
  for(int idx = t; idx < B * 32; idx += 1024){
    int b = idx >> 5, c = idx & 31;
    float M = -INFINITY, SS = 0.f, VV = 0.f;
    #pragma unroll 4
    for(int k = 0; k < S; ++k){
      int p = (b * S + k) * 32 + c;
      float mo = pM[p], so = pS[p], vo = pV[p];
      float mn = fmaxf(M, mo);
      float ea = (M  > -INFINITY) ? __expf(M  - mn) : 0.f;
      float eb = (mo > -INFINITY) ? __expf(mo - mn) : 0.f;
      SS = SS * ea + so * eb; VV = VV * ea + vo * eb; M = mn;
    }
    gs[idx] = VV / (SS + 1e-16f);
  }
  __syncthreads();
  if(t < B){
    float gr[32];
    #pragma unroll
    for(int k = 0; k < 32; ++k) gr[k] = gs[t * 32 + k];
    float h1[16];
    #pragma unroll
    for(int j = 0; j < 16; ++j){
      float acc = bl1[j];
      #pragma unroll
      for(int k = 0; k < 32; ++k) acc = fmaf(gr[k], Wl1[k * 16 + j], acc);
      h1[j] = eluf(acc);
    }
    float l0 = bl2[0], l1 = bl2[1];
    #pragma unroll
    for(int k = 0; k < 16; ++k){
      l0 = fmaf(h1[k], Wl2[k * 2 + 0], l0);
      l1 = fmaf(h1[k], Wl2[k * 2 + 1], l1);
    }
    float mx = fmaxf(l0, l1);
    float lse = mx + __logf(__expf(l0 - mx) + __expf(l1 - mx));
    out[t * 2 + 0] = l0 - lse;
    out[t * 2 + 1] = l1 - lse;
  }
}

extern "C" void kernel_launch(void* const* d_in, const int* in_sizes, int n_in,
                              void* d_out, int out_size, void* d_ws, size_t ws_size,
                              hipStream_t stream){
  const float* x     = (const float*)d_in[0];
  const int*   ei    = (const int*)d_in[1];
  const int*   batch = (const int*)d_in[2];
  const float* W1 = (const float*)d_in[3];
  const float* a1s = (const float*)d_in[4];
  const float* a1d = (const float*)d_in[5];
  const float* b1 = (const float*)d_in[6];
  const float* W2 = (const float*)d_in[7];
  const float* a2s = (const float*)d_in[8];
  const float* a2d = (const float*)d_in[9];
  const float* b2 = (const float*)d_in[10];
  const float* W3 = (const float*)d_in[11];
  const float* a3s = (const float*)d_in[12];
  const float* a3d = (const float*)d_in[13];
  const float* b3 = (const float*)d_in[14];
  const float* Wg1 = (const float*)d_in[15];
  const float* bg1 = (const float*)d_in[16];
  const float* Wg2 = (const float*)d_in[17];
  const float* bg2 = (const float*)d_in[18];
  const float* t   = (const float*)d_in[19];
  const float* Wl1 = (const float*)d_in[20];
  const float* bl1 = (const float*)d_in[21];
  const float* Wl2 = (const float*)d_in[22];
  const float* bl2 = (const float*)d_in[23];

  const int N = in_sizes[0];
  const int E = in_sizes[1] / 2;
  const int B = out_size / 2;
  const int ET = E + N;
  float* out = (float*)d_out;
  constexpr int BS = 32;                         // chunks per graph for batch agg

  // ---- workspace layout ----
  char* p = (char*)d_ws;
  short* Hbf  = (short*)p;            p += (size_t)N * 128 * 2;   // gemm/layer out (bf16)
  short* Abf  = (short*)p;            p += (size_t)N * 128 * 2;   // agg out (bf16)
  float* A32  = (float*)p;            p += (size_t)N * 32 * 4;    // final GCN out (fp32)
  float* as_  = (float*)p;            p += (size_t)N * 4;
  float* ad_  = (float*)p;            p += (size_t)N * 4;
  float* dinv = (float*)p;            p += (size_t)N * 4;
  int*   deg    = (int*)p;            p += (size_t)N * 4;
  int*   rowptr = (int*)p;            p += (size_t)(N + 1) * 4;
  int*   cursor = (int*)p;            p += (size_t)N * 4;
  int*   csr    = (int*)p;            p += (size_t)ET * 4;
  int*   bsum   = (int*)p;            p += (size_t)1024 * 4;
  p = alignp(p, 16);
  short* Wp2  = (short*)p;            p += 128 * 128 * 2;
  short* Wp3  = (short*)p;            p += 128 * 128 * 2;
  short* Wpg1 = (short*)p;            p += 128 * 64 * 2;
  short* Wpg2 = (short*)p;            p += 64 * 32 * 2;
  p = alignp(p, 16);
  float* pM   = (float*)p;            p += (size_t)B * BS * 32 * 4;
  float* pSb  = (float*)p;            p += (size_t)B * BS * 32 * 4;
  float* pV   = (float*)p;            p += (size_t)B * BS * 32 * 4;

  const int T = 256;
  const int gW2  = cdiv((long)N * 32, T);        // 2-dst-per-wave grids
  const int gG   = cdiv(N, 128);                 // mfma gemm: 128 rows/block (32/wave)
  const int NB   = cdiv(N, 256);                 // scan blocks (<=1024)
  const int Pdiv = cdiv(N, 8);                   // XCD dst-partition width

  // ---------- CSR build ----------
  hipMemsetAsync(deg, 0, (size_t)N * 4, stream);
  k_deg_count8<<<dim3(2048), dim3(T), 0, stream>>>(ei, E, Pdiv, deg);
  k_scan_part<<<dim3(NB), dim3(256), 0, stream>>>(deg, bsum, N);
  k_scan_mid<<<dim3(1), dim3(1024), 0, stream>>>(bsum, NB, rowptr, N);
  k_scan_fin<<<dim3(NB), dim3(256), 0, stream>>>(deg, bsum, rowptr, cursor, dinv, N);
  k_fill8<<<dim3(2048), dim3(T), 0, stream>>>(ei, E, N, Pdiv, cursor, csr);

  // ---------- prep: weight packs + GAT layer 1 outer product + dots ----------
  k_prep<<<dim3(21 + cdiv((long)N * 16, T)), dim3(T), 0, stream>>>(
      W2, W3, Wg1, Wg2, W1, a1s, a1d, x, Wp2, Wp3, Wpg1, Wpg2, Hbf, as_, ad_, N);
  k_gat_agg<<<dim3(gW2), dim3(T), 0, stream>>>(rowptr, csr, as_, ad_, Hbf, b1, Abf, N);

  // ---------- GAT layer 2 (128 -> 128) ----------
  k_gemm_mfma<128,128,true><<<dim3(gG), dim3(T), 0, stream>>>(Abf, Wp2, Hbf, a2s, a2d, as_, ad_, N);
  k_gat_agg<<<dim3(gW2), dim3(T), 0, stream>>>(rowptr, csr, as_, ad_, Hbf, b2, Abf, N);

  // ---------- GAT layer 3 (128 -> 128) ----------
  k_gemm_mfma<128,128,true><<<dim3(gG), dim3(T), 0, stream>>>(Abf, Wp3, Hbf, a3s, a3d, as_, ad_, N);
  k_gat_agg<<<dim3(gW2), dim3(T), 0, stream>>>(rowptr, csr, as_, ad_, Hbf, b3, Abf, N);

  // ---------- GCN layer 1 (128 -> 64) ----------
  k_gemm_mfma<128,64,false><<<dim3(gG), dim3(T), 0, stream>>>(Abf, Wpg1, Hbf, nullptr, nullptr, nullptr, nullptr, N);
  k_gcn_agg<64,true><<<dim3(gW2), dim3(T), 0, stream>>>(rowptr, csr, dinv, Hbf, bg1, Abf, (float*)nullptr, N);

  // ---------- GCN layer 2 (64 -> 32) ----------
  k_gemm_mfma<64,32,false><<<dim3(gG), dim3(T), 0, stream>>>(Abf, Wpg2, Hbf, nullptr, nullptr, nullptr, nullptr, N);
  k_gcn_agg<32,false><<<dim3(gW2), dim3(T), 0, stream>>>(rowptr, csr, dinv, Hbf, bg2, (short*)nullptr, A32, N);

  // ---------- per-graph softmax aggregation (chunked online) + heads ----------
  k_bagg_part<BS><<<dim3(B * BS), dim3(256), 0, stream>>>(A32, batch, t, pM, pSb, pV, N);
  k_final<BS><<<dim3(1), dim3(1024), 0, stream>>>(pM, pSb, pV, Wl1, bl1, Wl2, bl2, out, B);
}

// Round 13
// 255.381 us; speedup vs baseline: 1.0864x; 1.0864x over previous
//
#include <hip/hip_runtime.h>
#include <math.h>

static inline int cdiv(long a, long b){ return (int)((a + b - 1) / b); }
static inline char* alignp(char* p, size_t a){ return (char*)(((uintptr_t)p + a - 1) & ~(uintptr_t)(a - 1)); }

typedef __attribute__((ext_vector_type(8))) short bf16x8;
typedef __attribute__((ext_vector_type(4))) short bf16x4;
typedef __attribute__((ext_vector_type(4))) float f32x4;

__device__ __forceinline__ float lrelu(float x){ return x > 0.f ? x : 0.2f * x; }
__device__ __forceinline__ float eluf(float x){ return x > 0.f ? x : __expf(x) - 1.f; }
__device__ __forceinline__ short f2bf(float f){            // RNE f32 -> bf16 bits
  unsigned u = __float_as_uint(f);
  return (short)((u + 0x7FFFu + ((u >> 16) & 1u)) >> 16);
}
__device__ __forceinline__ float bflo(unsigned v){ return __uint_as_float(v << 16); }
__device__ __forceinline__ float bfhi(unsigned v){ return __uint_as_float(v & 0xFFFF0000u); }

// ======================= MFMA GEMM: 16 rows per wave (round-10 proven config) =======================
template<int K, int FOUT, bool DOTS>
__global__ void k_gemm_mfma(const short* __restrict__ Abf, const short* __restrict__ Wp,
                            short* __restrict__ outb,
                            const float* __restrict__ av_s, const float* __restrict__ av_d,
                            float* __restrict__ as_, float* __restrict__ ad_, int N){
  constexpr int NKS = K / 32, NCT = FOUT / 16;
  int wid  = threadIdx.x >> 6;
  int lane = threadIdx.x & 63;
  int rowbase = (blockIdx.x * 4 + wid) * 16;
  if(rowbase >= N) return;
  int arow = rowbase + (lane & 15);
  if(arow >= N) arow = N - 1;                     // clamp; clamped rows never stored
  f32x4 acc[NCT] = {};
  const short* ap = Abf + (long)arow * K + (lane >> 4) * 8;
  #pragma unroll
  for(int ks = 0; ks < NKS; ++ks){
    bf16x8 a = *(const bf16x8*)(ap + ks * 32);
    #pragma unroll
    for(int ct = 0; ct < NCT; ++ct){
      bf16x8 b = *(const bf16x8*)(Wp + ((ks * NCT + ct) * 64 + lane) * 8);
      acc[ct] = __builtin_amdgcn_mfma_f32_16x16x32_bf16(a, b, acc[ct], 0, 0, 0);
    }
  }
  int r0 = rowbase + (lane >> 4) * 4;             // D: row=(lane>>4)*4+j, col=lane&15
  int c0 = lane & 15;
  #pragma unroll
  for(int j = 0; j < 4; ++j){
    int r = r0 + j;
    if(r < N){
      #pragma unroll
      for(int ct = 0; ct < NCT; ++ct)
        outb[(long)r * FOUT + ct * 16 + c0] = f2bf(acc[ct][j]);
    }
  }
  if(DOTS){
    float avs[NCT], avd[NCT];
    #pragma unroll
    for(int ct = 0; ct < NCT; ++ct){ avs[ct] = av_s[ct * 16 + c0]; avd[ct] = av_d[ct * 16 + c0]; }
    #pragma unroll
    for(int j = 0; j < 4; ++j){
      float ps = 0.f, pd = 0.f;
      #pragma unroll
      for(int ct = 0; ct < NCT; ++ct){
        float hv = acc[ct][j];
        ps = fmaf(hv, avs[ct], ps);
        pd = fmaf(hv, avd[ct], pd);
      }
      #pragma unroll
      for(int off = 1; off < 16; off <<= 1){
        ps += __shfl_xor(ps, off);
        pd += __shfl_xor(pd, off);
      }
      int r = r0 + j;
      if(c0 == 0 && r < N){ as_[r] = ps; ad_[r] = pd; }
    }
  }
}

// ======================= merged prep: weight packs (blocks 0-20) + layer1 (blocks 21+) =======================
template<int K, int FOUT>
__device__ __forceinline__ void pack_dev(const float* __restrict__ W, short* __restrict__ Wp, int idx){
  constexpr int NKS = K / 32, NCT = FOUT / 16;
  if(idx >= NKS * NCT * 64) return;
  int lane = idx & 63;
  int ct = (idx >> 6) % NCT;
  int ks = (idx >> 6) / NCT;
  int col = ct * 16 + (lane & 15);
  int kb  = ks * 32 + (lane >> 4) * 8;
  #pragma unroll
  for(int j = 0; j < 8; ++j) Wp[idx * 8 + j] = f2bf(W[(kb + j) * FOUT + col]);
}
__global__ void k_prep(const float* __restrict__ W2, const float* __restrict__ W3,
                       const float* __restrict__ Wg1, const float* __restrict__ Wg2,
                       const float* __restrict__ W1, const float* __restrict__ a1s,
                       const float* __restrict__ a1d, const float* __restrict__ x,
                       short* __restrict__ Wp2, short* __restrict__ Wp3,
                       short* __restrict__ Wpg1, short* __restrict__ Wpg2,
                       short* __restrict__ outb, float* __restrict__ as_,
                       float* __restrict__ ad_, int N){
  int b = blockIdx.x;
  if(b < 8){       pack_dev<128,128>(W2,  Wp2,  b * 256 + threadIdx.x); return; }
  if(b < 16){      pack_dev<128,128>(W3,  Wp3,  (b - 8) * 256 + threadIdx.x); return; }
  if(b < 20){      pack_dev<128, 64>(Wg1, Wpg1, (b - 16) * 256 + threadIdx.x); return; }
  if(b == 20){     pack_dev< 64, 32>(Wg2, Wpg2, threadIdx.x); return; }
  // layer-1 blocks: self-compute S = (W1.a1s, W1.a1d), then outer product + dots
  __shared__ float s1[128], s2[128];
  int t = threadIdx.x;
  if(t < 128){ float w = W1[t]; s1[t] = w * a1s[t]; s2[t] = w * a1d[t]; }
  __syncthreads();
  for(int off = 64; off > 0; off >>= 1){
    if(t < off){ s1[t] += s1[t + off]; s2[t] += s2[t + off]; }
    __syncthreads();
  }
  float S0 = s1[0], S1 = s2[0];
  long idx = (long)(b - 21) * blockDim.x + t;
  if(idx >= (long)N * 16) return;
  int node = (int)(idx >> 4), j8 = ((int)idx & 15) * 8;
  float xv = x[node];
  float4 w0 = *(const float4*)(W1 + j8);
  float4 w1 = *(const float4*)(W1 + j8 + 4);
  bf16x8 v;
  v[0] = f2bf(xv * w0.x); v[1] = f2bf(xv * w0.y);
  v[2] = f2bf(xv * w0.z); v[3] = f2bf(xv * w0.w);
  v[4] = f2bf(xv * w1.x); v[5] = f2bf(xv * w1.y);
  v[6] = f2bf(xv * w1.z); v[7] = f2bf(xv * w1.w);
  *(bf16x8*)(outb + (long)node * 128 + j8) = v;
  if((idx & 15) == 0){ as_[node] = xv * S0; ad_[node] = xv * S1; }
}

// ======================= CSR build (dst-sorted, with self-loops) =======================
// deg[] is memset(0); the self-loop "+1" is folded into the scans below.
// XCD-partitioned: block p=blockIdx&7 handles dst range [p*Pdiv,(p+1)*Pdiv) only
__global__ void k_deg_count8(const int* __restrict__ ei, int E, int Pdiv,
                             int* __restrict__ deg){
  int p = blockIdx.x & 7;
  int lo = p * Pdiv, hi = lo + Pdiv;
  long stride = (long)(gridDim.x >> 3) * blockDim.x;
  for(long e = (long)(blockIdx.x >> 3) * blockDim.x + threadIdx.x; e < E; e += stride){
    int d = ei[E + e];
    if(d >= lo && d < hi) atomicAdd(&deg[d], 1);
  }
}

// ---- hierarchical exclusive scan of (deg[N]+1) -> rowptr[N+1], cursor[N], dinv[N] ----
__global__ void k_scan_part(const int* __restrict__ deg, int* __restrict__ bsum, int N){
  __shared__ int red[256];
  int i = blockIdx.x * 256 + threadIdx.x;
  int v = (i < N) ? deg[i] + 1 : 0;
  red[threadIdx.x] = v;
  __syncthreads();
  #pragma unroll
  for(int off = 128; off > 0; off >>= 1){
    if(threadIdx.x < off) red[threadIdx.x] += red[threadIdx.x + off];
    __syncthreads();
  }
  if(threadIdx.x == 0) bsum[blockIdx.x] = red[0];
}
__global__ void k_scan_mid(int* __restrict__ bsum, int NB, int* __restrict__ rowptr, int N){
  __shared__ int buf[1024];
  int t = threadIdx.x;
  int v = (t < NB) ? bsum[t] : 0;
  buf[t] = v;
  __syncthreads();
  for(int off = 1; off < 1024; off <<= 1){
    int u = (t >= off) ? buf[t - off] : 0;
    __syncthreads();
    buf[t] += u;
    __syncthreads();
  }
  if(t < NB) bsum[t] = buf[t] - v;                // exclusive
  if(t == 1023) rowptr[N] = buf[1023];
}
__global__ void k_scan_fin(const int* __restrict__ deg, const int* __restrict__ bsum,
                           int* __restrict__ rowptr, int* __restrict__ cursor,
                           float* __restrict__ dinv, int N){
  __shared__ int buf[256];
  int i = blockIdx.x * 256 + threadIdx.x;
  int t = threadIdx.x;
  int v = (i < N) ? deg[i] + 1 : 0;
  buf[t] = v;
  __syncthreads();
  #pragma unroll
  for(int off = 1; off < 256; off <<= 1){
    int u = (t >= off) ? buf[t - off] : 0;
    __syncthreads();
    buf[t] += u;
    __syncthreads();
  }
  if(i < N){
    int ex = buf[t] - v + bsum[blockIdx.x];
    rowptr[i] = ex; cursor[i] = ex;
    dinv[i] = rsqrtf((float)v);                   // v >= 1 (self-loop)
  }
}

// XCD-partitioned CSR fill
__global__ void k_fill8(const int* __restrict__ ei, int E, int N, int Pdiv,
                        int* __restrict__ cursor, int* __restrict__ csr){
  int p = blockIdx.x & 7;
  int lo = p * Pdiv, hi = lo + Pdiv;
  long ET = (long)E + N;
  long stride = (long)(gridDim.x >> 3) * blockDim.x;
  for(long e = (long)(blockIdx.x >> 3) * blockDim.x + threadIdx.x; e < ET; e += stride){
    int d = (e < E) ? ei[E + e] : (int)(e - E);
    if(d < lo || d >= hi) continue;
    int s = (e < E) ? ei[e] : d;
    int pos = atomicAdd(&cursor[d], 1);
    csr[pos] = s;
  }
}

// ======================= fused GAT aggregation: TWO dst per wave, 4-deep load batching =======================
__global__ void k_gat_agg(const int* __restrict__ rowptr, const int* __restrict__ csr,
                          const float* __restrict__ as_, const float* __restrict__ ad_,
                          const short* __restrict__ h, const float* __restrict__ bias,
                          short* __restrict__ out, int N){
  int pair = (int)(((long)blockIdx.x * blockDim.x + threadIdx.x) >> 6);
  if(pair * 2 >= N) return;
  int lane = threadIdx.x & 63;
  int half = lane >> 5, hl = lane & 31;
  int w = pair * 2 + half;
  bool active = (w < N);
  int start = 0, end = 0, deg = 0;
  float add = 0.f;
  if(active){ start = rowptr[w]; end = rowptr[w + 1]; deg = end - start; add = ad_[w]; }

  int s_reg = 0;
  float logit = -INFINITY;
  if(hl < deg){                                  // implies active
    s_reg = csr[start + hl];
    logit = lrelu(as_[s_reg] + add);
  }
  float m, inv, alpha_reg;
  if(deg <= 32){
    // fast path: per-half 3-phase softmax (offsets <=16 never cross the half)
    m = logit;
    #pragma unroll
    for(int off = 16; off > 0; off >>= 1) m = fmaxf(m, __shfl_xor(m, off));
    float e = __expf(logit - m);                 // inactive lanes: exp(-INF)=0
    float ssum = e;
    #pragma unroll
    for(int off = 16; off > 0; off >>= 1) ssum += __shfl_xor(ssum, off);
    inv = 1.f / (ssum + 1e-16f);
    alpha_reg = e * inv;
  }else{
    // rare overflow: per-lane online over strided edges, then per-half merge
    float mm = logit, ssum = (hl < deg) ? 1.f : 0.f;
    for(int e = start + hl + 32; e < end; e += 32){
      int s = csr[e];
      float l = lrelu(as_[s] + add);
      if(l > mm){ ssum = ssum * __expf(mm - l) + 1.f; mm = l; }
      else        ssum += __expf(l - mm);
    }
    #pragma unroll
    for(int off = 16; off > 0; off >>= 1){
      float mo = __shfl_xor(mm, off);
      float so = __shfl_xor(ssum, off);
      float mn = fmaxf(mm, mo);
      float ea = (mm > -INFINITY) ? __expf(mm - mn) : 0.f;
      float eb = (mo > -INFINITY) ? __expf(mo - mn) : 0.f;
      ssum = ssum * ea + so * eb;
      mm = mn;
    }
    m = mm;
    inv = 1.f / (ssum + 1e-16f);
    alpha_reg = __expf(logit - m) * inv;
  }

  // phase B: per half, 8 edges per outer iter (4 per 16-lane subgroup), all 4 loads
  // issued before any FMA -> 4 gathers in flight. Invalid slots clamp to edge 0 with a=0.
  float acc[8] = {};
  int nb = deg < 32 ? deg : 32;
  int gg = hl >> 4;
  int fo = (hl & 15) * 8;
  int base = half << 5;
  const short* hf = h + fo;
  for(int k = 0; k < nb; k += 8){
    uint4 hv[4]; float av[4];
    #pragma unroll
    for(int u = 0; u < 4; ++u){
      int idx = k + 2 * u + gg;
      bool ok = idx < nb;
      int sl = base + (ok ? idx : 0);
      float a = __shfl(alpha_reg, sl);
      av[u] = ok ? a : 0.f;
      int s  = __shfl(s_reg, sl);
      hv[u] = *(const uint4*)(hf + (long)s * 128);
    }
    #pragma unroll
    for(int u = 0; u < 4; ++u){
      acc[0] = fmaf(av[u], bflo(hv[u].x), acc[0]);
      acc[1] = fmaf(av[u], bfhi(hv[u].x), acc[1]);
      acc[2] = fmaf(av[u], bflo(hv[u].y), acc[2]);
      acc[3] = fmaf(av[u], bfhi(hv[u].y), acc[3]);
      acc[4] = fmaf(av[u], bflo(hv[u].z), acc[4]);
      acc[5] = fmaf(av[u], bfhi(hv[u].z), acc[5]);
      acc[6] = fmaf(av[u], bflo(hv[u].w), acc[6]);
      acc[7] = fmaf(av[u], bfhi(hv[u].w), acc[7]);
    }
  }
  for(int e = start + 32; e < end; ++e){          // rare overflow (subgroup 0 of half)
    if(hl < 16){
      int s = csr[e];
      float l = lrelu(as_[s] + add);
      float a = __expf(l - m) * inv;
      uint4 hv = *(const uint4*)(hf + (long)s * 128);
      acc[0] = fmaf(a, bflo(hv.x), acc[0]);
      acc[1] = fmaf(a, bfhi(hv.x), acc[1]);
      acc[2] = fmaf(a, bflo(hv.y), acc[2]);
      acc[3] = fmaf(a, bfhi(hv.y), acc[3]);
      acc[4] = fmaf(a, bflo(hv.z), acc[4]);
      acc[5] = fmaf(a, bfhi(hv.z), acc[5]);
      acc[6] = fmaf(a, bflo(hv.w), acc[6]);
      acc[7] = fmaf(a, bfhi(hv.w), acc[7]);
    }
  }
  #pragma unroll
  for(int j = 0; j < 8; ++j) acc[j] += __shfl_xor(acc[j], 16);
  if(active && hl < 16){
    float4 b0 = *(const float4*)(bias + fo);
    float4 b1 = *(const float4*)(bias + fo + 4);
    bf16x8 v;
    v[0] = f2bf(eluf(acc[0] + b0.x)); v[1] = f2bf(eluf(acc[1] + b0.y));
    v[2] = f2bf(eluf(acc[2] + b0.z)); v[3] = f2bf(eluf(acc[3] + b0.w));
    v[4] = f2bf(eluf(acc[4] + b1.x)); v[5] = f2bf(eluf(acc[5] + b1.y));
    v[6] = f2bf(eluf(acc[6] + b1.z)); v[7] = f2bf(eluf(acc[7] + b1.w));
    *(bf16x8*)(out + (long)w * 128 + fo) = v;
  }
}

// ======================= fused GCN aggregation: TWO dst per wave, 4-deep load batching =======================
template<int F, bool BFOUT>
__global__ void k_gcn_agg(const int* __restrict__ rowptr, const int* __restrict__ csr,
                          const float* __restrict__ dinv, const short* __restrict__ h,
                          const float* __restrict__ bias, short* __restrict__ out_bf,
                          float* __restrict__ out_f, int N){
  constexpr int FPL = F / 16;                     // features per lane (4 or 2)
  int pair = (int)(((long)blockIdx.x * blockDim.x + threadIdx.x) >> 6);
  if(pair * 2 >= N) return;
  int lane = threadIdx.x & 63;
  int half = lane >> 5, hl = lane & 31;
  int w = pair * 2 + half;
  bool active = (w < N);
  int start = 0, end = 0, deg = 0;
  float dd = 0.f;
  if(active){ start = rowptr[w]; end = rowptr[w + 1]; deg = end - start; dd = dinv[w]; }
  int s_reg = 0; float dv_reg = 0.f;
  if(hl < deg){
    s_reg = csr[start + hl];
    dv_reg = dinv[s_reg];
  }
  float acc[FPL] = {};
  int nb = deg < 32 ? deg : 32;
  int gg = hl >> 4;
  int fo = (hl & 15) * FPL;
  int base = half << 5;
  const short* hf = h + fo;
  for(int k = 0; k < nb; k += 8){
    uint2 hv4[4]; unsigned hv2[4]; float nv[4];
    #pragma unroll
    for(int u = 0; u < 4; ++u){
      int idx = k + 2 * u + gg;
      bool ok = idx < nb;
      int sl = base + (ok ? idx : 0);
      float nrm = dd * __shfl(dv_reg, sl);
      nv[u] = ok ? nrm : 0.f;
      int s = __shfl(s_reg, sl);
      if(FPL == 4) hv4[u] = *(const uint2*)(hf + (long)s * F);
      else         hv2[u] = *(const unsigned*)(hf + (long)s * F);
    }
    #pragma unroll
    for(int u = 0; u < 4; ++u){
      if(FPL == 4){
        acc[0] = fmaf(nv[u], bflo(hv4[u].x), acc[0]);
        acc[1] = fmaf(nv[u], bfhi(hv4[u].x), acc[1]);
        acc[2] = fmaf(nv[u], bflo(hv4[u].y), acc[2]);
        acc[3] = fmaf(nv[u], bfhi(hv4[u].y), acc[3]);
      }else{
        acc[0] = fmaf(nv[u], bflo(hv2[u]), acc[0]);
        acc[1] = fmaf(nv[u], bfhi(hv2[u]), acc[1]);
      }
    }
  }
  for(int e = start + 32; e < end; ++e){          // rare overflow (subgroup 0 of half)
    if(hl < 16){
      int s = csr[e];
      float nrm = dd * dinv[s];
      if(FPL == 4){
        uint2 hv = *(const uint2*)(hf + (long)s * F);
        acc[0] = fmaf(nrm, bflo(hv.x), acc[0]);
        acc[1] = fmaf(nrm, bfhi(hv.x), acc[1]);
        acc[2] = fmaf(nrm, bflo(hv.y), acc[2]);
        acc[3] = fmaf(nrm, bfhi(hv.y), acc[3]);
      }else{
        unsigned hv = *(const unsigned*)(hf + (long)s * F);
        acc[0] = fmaf(nrm, bflo(hv), acc[0]);
        acc[1] = fmaf(nrm, bfhi(hv), acc[1]);
      }
    }
  }
  #pragma unroll
  for(int j = 0; j < FPL; ++j) acc[j] += __shfl_xor(acc[j], 16);
  if(active && hl < 16){
    if(BFOUT){
      if(FPL == 4){
        bf16x4 v;
        #pragma unroll
        for(int j = 0; j < 4; ++j) v[j] = f2bf(eluf(acc[j] + bias[fo + j]));
        *(bf16x4*)(out_bf + (long)w * F + fo) = v;
      }else{
        #pragma unroll
        for(int j = 0; j < FPL; ++j)
          out_bf[(long)w * F + fo + j] = f2bf(eluf(acc[j] + bias[fo + j]));
      }
    }else{
      if(FPL == 2){
        float2 v2 = make_float2(eluf(acc[0] + bias[fo]), eluf(acc[1] + bias[fo + 1]));
        *(float2*)(out_f + (long)w * F + fo) = v2;
      }else{
        #pragma unroll
        for(int j = 0; j < FPL; ++j)
          out_f[(long)w * F + fo + j] = eluf(acc[j] + bias[fo + j]);
      }
    }
  }
}

// ============ per-graph softmax aggregation: chunked online (m,s,v) + combine ============
template<int S>
__global__ void k_bagg_part(const float* __restrict__ h, const int* __restrict__ batch,
                            const float* __restrict__ t, float* __restrict__ pM,
                            float* __restrict__ pS, float* __restrict__ pV, int N){
  int chunk = blockIdx.x;
  int b = chunk / S, s = chunk % S;
  __shared__ int s_lo, s_hi;
  if(threadIdx.x == 0){
    int lo = 0, hi = N;
    while(lo < hi){ int mid = (lo + hi) >> 1; if(batch[mid] < b) lo = mid + 1; else hi = mid; }
    s_lo = lo;
    int lo2 = lo, hi2 = N;
    while(lo2 < hi2){ int mid = (lo2 + hi2) >> 1; if(batch[mid] < b + 1) lo2 = mid + 1; else hi2 = mid; }
    s_hi = lo2;
  }
  __syncthreads();
  int lo = s_lo, hi = s_hi;
  int len = hi - lo;
  int per = (len + S - 1) / S;
  int clo = lo + s * per;
  int chi = clo + per; if(chi > hi) chi = hi;
  float tv = t[0];
  int c = threadIdx.x & 31, r = threadIdx.x >> 5;   // 8 rows x 32 channels

  float m = -INFINITY, ss = 0.f, vv = 0.f;
  for(int i = clo + r; i < chi; i += 8){
    float hv = h[(long)i * 32 + c];
    float l = hv * tv;
    if(l > m){
      float e = (m > -INFINITY) ? __expf(m - l) : 0.f;
      ss = ss * e + 1.f; vv = vv * e + hv; m = l;
    }else{
      float e = __expf(l - m);
      ss += e; vv += e * hv;
    }
  }
  __shared__ float rm[8][32], rs[8][32], rv[8][32];
  rm[r][c] = m; rs[r][c] = ss; rv[r][c] = vv;
  __syncthreads();
  if(r == 0){
    float M = rm[0][c], SS = rs[0][c], VV = rv[0][c];
    #pragma unroll
    for(int k = 1; k < 8; ++k){
      float mo = rm[k][c], so = rs[k][c], vo = rv[k][c];
      float mn = fmaxf(M, mo);
      float ea = (M  > -INFINITY) ? __expf(M  - mn) : 0.f;
      float eb = (mo > -INFINITY) ? __expf(mo - mn) : 0.f;
      SS = SS * ea + so * eb; VV = VV * ea + vo * eb; M = mn;
    }
    pM[chunk * 32 + c] = M; pS[chunk * 32 + c] = SS; pV[chunk * 32 + c] = VV;
  }
}
template<int S>
__global__ void k_bagg_comb(const float* __restrict__ pM, const float* __restrict__ pS,
                            const float* __restrict__ pV, float* __restrict__ g, int B){
  int idx = blockIdx.x * blockDim.x + threadIdx.x;  // b*32 + c
  if(idx >= B * 32) return;
  int b = idx >> 5, c = idx & 31;
  float M = -INFINITY, SS = 0.f, VV = 0.f;
  #pragma unroll 4
  for(int k = 0; k < S; ++k){
    int p = (b * S + k) * 32 + c;
    float mo = pM[p], so = pS[p], vo = pV[p];
    float mn = fmaxf(M, mo);
    float ea = (M  > -INFINITY) ? __expf(M  - mn) : 0.f;
    float eb = (mo > -INFINITY) ? __expf(mo - mn) : 0.f;
    SS = SS * ea + so * eb; VV = VV * ea + vo * eb; M = mn;
  }
  g[idx] = VV / (SS + 1e-16f);
}

// ---- heads ----
__global__ void k_head(const float* __restrict__ g, const float* __restrict__ Wl1,
                       const float* __restrict__ bl1, const float* __restrict__ Wl2,
                       const float* __restrict__ bl2, float* __restrict__ out, int B){
  int b = blockIdx.x * blockDim.x + threadIdx.x;
  if(b >= B) return;
  float gr[32];
  #pragma unroll
  for(int k = 0; k < 32; ++k) gr[k] = g[b * 32 + k];
  float h1[16];
  #pragma unroll
  for(int j = 0; j < 16; ++j){
    float acc = bl1[j];
    #pragma unroll
    for(int k = 0; k < 32; ++k) acc = fmaf(gr[k], Wl1[k * 16 + j], acc);
    h1[j] = eluf(acc);
  }
  float l0 = bl2[0], l1 = bl2[1];
  #pragma unroll
  for(int k = 0; k < 16; ++k){
    l0 = fmaf(h1[k], Wl2[k * 2 + 0], l0);
    l1 = fmaf(h1[k], Wl2[k * 2 + 1], l1);
  }
  float mx = fmaxf(l0, l1);
  float lse = mx + __logf(__expf(l0 - mx) + __expf(l1 - mx));
  out[b * 2 + 0] = l0 - lse;
  out[b * 2 + 1] = l1 - lse;
}

extern "C" void kernel_launch(void* const* d_in, const int* in_sizes, int n_in,
                              void* d_out, int out_size, void* d_ws, size_t ws_size,
                              hipStream_t stream){
  const float* x     = (const float*)d_in[0];
  const int*   ei    = (const int*)d_in[1];
  const int*   batch = (const int*)d_in[2];
  const float* W1 = (const float*)d_in[3];
  const float* a1s = (const float*)d_in[4];
  const float* a1d = (const float*)d_in[5];
  const float* b1 = (const float*)d_in[6];
  const float* W2 = (const float*)d_in[7];
  const float* a2s = (const float*)d_in[8];
  const float* a2d = (const float*)d_in[9];
  const float* b2 = (const float*)d_in[10];
  const float* W3 = (const float*)d_in[11];
  const float* a3s = (const float*)d_in[12];
  const float* a3d = (const float*)d_in[13];
  const float* b3 = (const float*)d_in[14];
  const float* Wg1 = (const float*)d_in[15];
  const float* bg1 = (const float*)d_in[16];
  const float* Wg2 = (const float*)d_in[17];
  const float* bg2 = (const float*)d_in[18];
  const float* t   = (const float*)d_in[19];
  const float* Wl1 = (const float*)d_in[20];
  const float* bl1 = (const float*)d_in[21];
  const float* Wl2 = (const float*)d_in[22];
  const float* bl2 = (const float*)d_in[23];

  const int N = in_sizes[0];
  const int E = in_sizes[1] / 2;
  const int B = out_size / 2;
  const int ET = E + N;
  float* out = (float*)d_out;
  constexpr int BS = 32;                         // chunks per graph for batch agg

  // ---- workspace layout ----
  char* p = (char*)d_ws;
  short* Hbf  = (short*)p;            p += (size_t)N * 128 * 2;   // gemm/layer out (bf16)
  short* Abf  = (short*)p;            p += (size_t)N * 128 * 2;   // agg out (bf16)
  float* A32  = (float*)p;            p += (size_t)N * 32 * 4;    // final GCN out (fp32)
  float* as_  = (float*)p;            p += (size_t)N * 4;
  float* ad_  = (float*)p;            p += (size_t)N * 4;
  float* dinv = (float*)p;            p += (size_t)N * 4;
  int*   deg    = (int*)p;            p += (size_t)N * 4;
  int*   rowptr = (int*)p;            p += (size_t)(N + 1) * 4;
  int*   cursor = (int*)p;            p += (size_t)N * 4;
  int*   csr    = (int*)p;            p += (size_t)ET * 4;
  int*   bsum   = (int*)p;            p += (size_t)1024 * 4;
  p = alignp(p, 16);
  short* Wp2  = (short*)p;            p += 128 * 128 * 2;
  short* Wp3  = (short*)p;            p += 128 * 128 * 2;
  short* Wpg1 = (short*)p;            p += 128 * 64 * 2;
  short* Wpg2 = (short*)p;            p += 64 * 32 * 2;
  p = alignp(p, 16);
  float* pM   = (float*)p;            p += (size_t)B * BS * 32 * 4;
  float* pSb  = (float*)p;            p += (size_t)B * BS * 32 * 4;
  float* pV   = (float*)p;            p += (size_t)B * BS * 32 * 4;
  float* g    = (float*)p;

  const int T = 256;
  const int gW2  = cdiv((long)N * 32, T);        // 2-dst-per-wave grids
  const int gG   = cdiv(N, 64);                  // mfma gemm: 64 rows/block (16/wave)
  const int NB   = cdiv(N, 256);                 // scan blocks (<=1024)
  const int Pdiv = cdiv(N, 8);                   // XCD dst-partition width

  // ---------- CSR build ----------
  hipMemsetAsync(deg, 0, (size_t)N * 4, stream);
  k_deg_count8<<<dim3(2048), dim3(T), 0, stream>>>(ei, E, Pdiv, deg);
  k_scan_part<<<dim3(NB), dim3(256), 0, stream>>>(deg, bsum, N);
  k_scan_mid<<<dim3(1), dim3(1024), 0, stream>>>(bsum, NB, rowptr, N);
  k_scan_fin<<<dim3(NB), dim3(256), 0, stream>>>(deg, bsum, rowptr, cursor, dinv, N);
  k_fill8<<<dim3(2048), dim3(T), 0, stream>>>(ei, E, N, Pdiv, cursor, csr);

  // ---------- prep: weight packs + GAT layer 1 outer product + dots ----------
  k_prep<<<dim3(21 + cdiv((long)N * 16, T)), dim3(T), 0, stream>>>(
      W2, W3, Wg1, Wg2, W1, a1s, a1d, x, Wp2, Wp3, Wpg1, Wpg2, Hbf, as_, ad_, N);
  k_gat_agg<<<dim3(gW2), dim3(T), 0, stream>>>(rowptr, csr, as_, ad_, Hbf, b1, Abf, N);

  // ---------- GAT layer 2 (128 -> 128) ----------
  k_gemm_mfma<128,128,true><<<dim3(gG), dim3(T), 0, stream>>>(Abf, Wp2, Hbf, a2s, a2d, as_, ad_, N);
  k_gat_agg<<<dim3(gW2), dim3(T), 0, stream>>>(rowptr, csr, as_, ad_, Hbf, b2, Abf, N);

  // ---------- GAT layer 3 (128 -> 128) ----------
  k_gemm_mfma<128,128,true><<<dim3(gG), dim3(T), 0, stream>>>(Abf, Wp3, Hbf, a3s, a3d, as_, ad_, N);
  k_gat_agg<<<dim3(gW2), dim3(T), 0, stream>>>(rowptr, csr, as_, ad_, Hbf, b3, Abf, N);

  // ---------- GCN layer 1 (128 -> 64) ----------
  k_gemm_mfma<128,64,false><<<dim3(gG), dim3(T), 0, stream>>>(Abf, Wpg1, Hbf, nullptr, nullptr, nullptr, nullptr, N);
  k_gcn_agg<64,true><<<dim3(gW2), dim3(T), 0, stream>>>(rowptr, csr, dinv, Hbf, bg1, Abf, (float*)nullptr, N);

  // ---------- GCN layer 2 (64 -> 32) ----------
  k_gemm_mfma<64,32,false><<<dim3(gG), dim3(T), 0, stream>>>(Abf, Wpg2, Hbf, nullptr, nullptr, nullptr, nullptr, N);
  k_gcn_agg<32,false><<<dim3(gW2), dim3(T), 0, stream>>>(rowptr, csr, dinv, Hbf, bg2, (short*)nullptr, A32, N);

  // ---------- per-graph softmax aggregation (chunked online) ----------
  k_bagg_part<BS><<<dim3(B * BS), dim3(256), 0, stream>>>(A32, batch, t, pM, pSb, pV, N);
  k_bagg_comb<BS><<<dim3(cdiv(B * 32, 256)), dim3(256), 0, stream>>>(pM, pSb, pV, g, B);

  // ---------- MLP heads + log_softmax ----------
  k_head<<<dim3(cdiv(B, 64)), dim3(64), 0, stream>>>(g, Wl1, bl1, Wl2, bl2, out, B);
}